// Round 1
// baseline (726.514 us; speedup 1.0000x reference)
//
#include <hip/hip_runtime.h>

// Problem constants
#define C_DIM 512
#define V_DIM 1024

typedef __attribute__((ext_vector_type(8))) short short8;   // 8 bf16 (4 VGPRs)
typedef __attribute__((ext_vector_type(4))) float f32x4;

__device__ __forceinline__ short f2bf(float f) {
  unsigned int u = __float_as_uint(f);
  u += 0x7fffu + ((u >> 16) & 1u);           // RNE
  return (short)(u >> 16);
}

__device__ __forceinline__ float fast_tanh_f(float x) {
  // tanh(x) = 1 - 2/(exp(2x)+1); saturates correctly at +/-inf
  float e = __expf(2.0f * x);
  return fmaf(-2.0f, __builtin_amdgcn_rcpf(e + 1.0f), 1.0f);
}

// ---------------------------------------------------------------------------
// Kernel 1: cast W (V,C) fp32 -> bf16, swizzled into the exact LDS image the
// GEMM's B staging wants: chunk (vt,kc) = 16384 B block, inside it
// [vloc(256)][quad(4)][j(8)] with c = kc*32 + quad*8 + j.
// ---------------------------------------------------------------------------
__global__ __launch_bounds__(256) void wswz_kernel(const float* __restrict__ W,
                                                   char* __restrict__ wsw) {
  const int i = blockIdx.x * 256 + threadIdx.x;   // 65536 threads
  const int v = i >> 6;
  const int c0 = (i & 63) << 3;
  const float* wp = W + (size_t)v * C_DIM + c0;
  const f32x4 w0 = *(const f32x4*)(wp);
  const f32x4 w1 = *(const f32x4*)(wp + 4);
  short8 pk;
  pk[0] = f2bf(w0[0]); pk[1] = f2bf(w0[1]); pk[2] = f2bf(w0[2]); pk[3] = f2bf(w0[3]);
  pk[4] = f2bf(w1[0]); pk[5] = f2bf(w1[1]); pk[6] = f2bf(w1[2]); pk[7] = f2bf(w1[3]);
  const int vt = v >> 8, vloc = v & 255;
  const int kc = c0 >> 5, q = (c0 >> 3) & 3;
  char* dst = wsw + (size_t)(vt * 16 + kc) * 16384 + vloc * 64 + q * 16;
  *(short8*)dst = pk;
}

// ---------------------------------------------------------------------------
// Kernel 2: fused tanh(enc+pred) -> bf16 persistent A in LDS (128 KB), then
// GEMM vs swizzled W with double-buffered global_load_lds B staging.
// Block: 512 thr = 8 waves (2x4), wave tile 64x64, block tile 128 x 256(v),
// 4 v-tiles, K chunks of 32. LDS = 131072 (A) + 2*16384 (B) = 163840 B.
// ---------------------------------------------------------------------------
__global__ __launch_bounds__(512, 2) void joiner_kernel(
    const float* __restrict__ enc, const float* __restrict__ pred,
    const char* __restrict__ wsw, const float* __restrict__ bias,
    float* __restrict__ out) {
  extern __shared__ char smem[];
  const int tid = threadIdx.x;
  const int lane = tid & 63;
  const int w = tid >> 6;                 // wave 0..7
  const int blk = blockIdx.x;             // 1024 blocks
  const int n = blk >> 7;                 // batch
  const int r0 = blk << 7;                // global row base (row = (n*T+t)*U+u)
  const int t0 = (blk << 1) & 255;        // first of 2 t values

  // ---- Stage A: tanh(enc+pred) -> bf16, packed [kc(16)][row(128)][q(4)][j(8)]
  {
    const int row = tid >> 2;             // 0..127
    const int q = tid & 3;
    const float* ep = enc + (size_t)(n * 256 + t0 + (row >> 6)) * C_DIM + q * 8;
    const float* pp = pred + (size_t)(n * 64 + (row & 63)) * C_DIM + q * 8;
    char* adst = smem + row * 64 + q * 16;
#pragma unroll
    for (int s = 0; s < 16; ++s) {        // s == kc
      const f32x4 e0 = *(const f32x4*)(ep + s * 32);
      const f32x4 e1 = *(const f32x4*)(ep + s * 32 + 4);
      const f32x4 p0 = *(const f32x4*)(pp + s * 32);
      const f32x4 p1 = *(const f32x4*)(pp + s * 32 + 4);
      short8 pk;
      pk[0] = f2bf(fast_tanh_f(e0[0] + p0[0]));
      pk[1] = f2bf(fast_tanh_f(e0[1] + p0[1]));
      pk[2] = f2bf(fast_tanh_f(e0[2] + p0[2]));
      pk[3] = f2bf(fast_tanh_f(e0[3] + p0[3]));
      pk[4] = f2bf(fast_tanh_f(e1[0] + p1[0]));
      pk[5] = f2bf(fast_tanh_f(e1[1] + p1[1]));
      pk[6] = f2bf(fast_tanh_f(e1[2] + p1[2]));
      pk[7] = f2bf(fast_tanh_f(e1[3] + p1[3]));
      *(short8*)(adst + s * 8192) = pk;   // ds_write_b128, linear, conflict-free
    }
  }

  // ---- B staging: chunk g -> buffer g&1 (16 KB each), width-16 direct-to-LDS
  const size_t lanebyte = (size_t)(w * 1024 + lane * 16);
  auto stage_b = [&](int g2) {
    const char* src = wsw + (size_t)g2 * 16384 + lanebyte;
    char* dst = smem + 131072 + (g2 & 1) * 16384 + w * 1024;  // wave-uniform base
    __builtin_amdgcn_global_load_lds(
        (const __attribute__((address_space(1))) void*)src,
        (__attribute__((address_space(3))) void*)dst, 16, 0, 0);
    __builtin_amdgcn_global_load_lds(
        (const __attribute__((address_space(1))) void*)(src + 8192),
        (__attribute__((address_space(3))) void*)(dst + 8192), 16, 0, 0);
  };
  stage_b(0);

  const int wm = w >> 2, wn = w & 3;      // wave grid 2(m) x 4(n)
  const int l15 = lane & 15, qd = lane >> 4;
  const char* abase = smem + (wm * 64 + l15) * 64 + qd * 16;
  const char* bbase = smem + 131072 + (wn * 64 + l15) * 64 + qd * 16;

  f32x4 acc[4][4];
#pragma unroll
  for (int mt = 0; mt < 4; ++mt)
#pragma unroll
    for (int nt = 0; nt < 4; ++nt) acc[mt][nt] = (f32x4){0.f, 0.f, 0.f, 0.f};

#pragma unroll 2
  for (int g = 0; g < 64; ++g) {          // g = vt*16 + kc
    __syncthreads();                      // drains prefetch of chunk g (issued last iter)
    if (g < 63) stage_b(g + 1);           // safe: everyone is past reads of buf[(g+1)&1]
    const char* ap = abase + (g & 15) * 8192;
    const short8 a0 = *(const short8*)(ap);
    const short8 a1 = *(const short8*)(ap + 1024);
    const short8 a2 = *(const short8*)(ap + 2048);
    const short8 a3 = *(const short8*)(ap + 3072);
    const char* bp = bbase + (g & 1) * 16384;
    const short8 b0 = *(const short8*)(bp);
    const short8 b1 = *(const short8*)(bp + 1024);
    const short8 b2 = *(const short8*)(bp + 2048);
    const short8 b3 = *(const short8*)(bp + 3072);
    acc[0][0] = __builtin_amdgcn_mfma_f32_16x16x32_bf16(a0, b0, acc[0][0], 0, 0, 0);
    acc[0][1] = __builtin_amdgcn_mfma_f32_16x16x32_bf16(a0, b1, acc[0][1], 0, 0, 0);
    acc[0][2] = __builtin_amdgcn_mfma_f32_16x16x32_bf16(a0, b2, acc[0][2], 0, 0, 0);
    acc[0][3] = __builtin_amdgcn_mfma_f32_16x16x32_bf16(a0, b3, acc[0][3], 0, 0, 0);
    acc[1][0] = __builtin_amdgcn_mfma_f32_16x16x32_bf16(a1, b0, acc[1][0], 0, 0, 0);
    acc[1][1] = __builtin_amdgcn_mfma_f32_16x16x32_bf16(a1, b1, acc[1][1], 0, 0, 0);
    acc[1][2] = __builtin_amdgcn_mfma_f32_16x16x32_bf16(a1, b2, acc[1][2], 0, 0, 0);
    acc[1][3] = __builtin_amdgcn_mfma_f32_16x16x32_bf16(a1, b3, acc[1][3], 0, 0, 0);
    acc[2][0] = __builtin_amdgcn_mfma_f32_16x16x32_bf16(a2, b0, acc[2][0], 0, 0, 0);
    acc[2][1] = __builtin_amdgcn_mfma_f32_16x16x32_bf16(a2, b1, acc[2][1], 0, 0, 0);
    acc[2][2] = __builtin_amdgcn_mfma_f32_16x16x32_bf16(a2, b2, acc[2][2], 0, 0, 0);
    acc[2][3] = __builtin_amdgcn_mfma_f32_16x16x32_bf16(a2, b3, acc[2][3], 0, 0, 0);
    acc[3][0] = __builtin_amdgcn_mfma_f32_16x16x32_bf16(a3, b0, acc[3][0], 0, 0, 0);
    acc[3][1] = __builtin_amdgcn_mfma_f32_16x16x32_bf16(a3, b1, acc[3][1], 0, 0, 0);
    acc[3][2] = __builtin_amdgcn_mfma_f32_16x16x32_bf16(a3, b2, acc[3][2], 0, 0, 0);
    acc[3][3] = __builtin_amdgcn_mfma_f32_16x16x32_bf16(a3, b3, acc[3][3], 0, 0, 0);

    if ((g & 15) == 15) {                 // end of K for v-tile vt = g>>4
      const int vt = g >> 4;
      const int colb = vt * 256 + wn * 64 + l15;
#pragma unroll
      for (int nt = 0; nt < 4; ++nt) {
        const float bb = bias[colb + nt * 16];
#pragma unroll
        for (int mt = 0; mt < 4; ++mt) {
          // C/D layout: col = lane&15, row = (lane>>4)*4 + reg  [m89/m91]
          float* op = out + (size_t)(r0 + wm * 64 + mt * 16 + qd * 4) * V_DIM +
                      (colb + nt * 16);
          op[0 * V_DIM] = acc[mt][nt][0] + bb;
          op[1 * V_DIM] = acc[mt][nt][1] + bb;
          op[2 * V_DIM] = acc[mt][nt][2] + bb;
          op[3 * V_DIM] = acc[mt][nt][3] + bb;
          acc[mt][nt] = (f32x4){0.f, 0.f, 0.f, 0.f};
        }
      }
    }
  }
}

extern "C" void kernel_launch(void* const* d_in, const int* in_sizes, int n_in,
                              void* d_out, int out_size, void* d_ws, size_t ws_size,
                              hipStream_t stream) {
  const float* enc  = (const float*)d_in[0];   // (8,256,512)
  const float* pred = (const float*)d_in[1];   // (8,64,512)
  const float* W    = (const float*)d_in[2];   // (1024,512)
  const float* bias = (const float*)d_in[3];   // (1024,)
  float* out = (float*)d_out;                  // (8,256,64,1024)
  char* wsw = (char*)d_ws;                     // 1 MB swizzled bf16 W

  wswz_kernel<<<dim3(256), dim3(256), 0, stream>>>(W, wsw);

  // 160 KiB dynamic LDS (A 128K + 2x16K B buffers)
  (void)hipFuncSetAttribute((const void*)joiner_kernel,
                            hipFuncAttributeMaxDynamicSharedMemorySize, 163840);
  joiner_kernel<<<dim3(1024), dim3(512), 163840, stream>>>(enc, pred, wsw, bias, out);
}